// Round 3
// baseline (143.693 us; speedup 1.0000x reference)
//
#include <hip/hip_runtime.h>

#define NSPK 256
#define MUTT 64
#define DDIM 1024
#define NROW (NSPK * MUTT)   // 16384

using frag_ab  = __attribute__((ext_vector_type(8)))  short;   // 8 bf16 (4 VGPRs)
using frag_cd  = __attribute__((ext_vector_type(4)))  float;   // 4 fp32 acc (16x16)
using frag_c16 = __attribute__((ext_vector_type(16))) float;   // 16 fp32 acc (32x32)

static __device__ __forceinline__ unsigned short f32_to_bf16(float f) {
    unsigned int u = __float_as_uint(f);
    return (unsigned short)((u + 0x7FFFu + ((u >> 16) & 1u)) >> 16);   // RNE
}
static __device__ __forceinline__ unsigned int pack2(float a, float b) {
    return (unsigned)f32_to_bf16(a) | ((unsigned)f32_to_bf16(b) << 16);
}
static __device__ __forceinline__ void gload16(const void* g, void* l) {
    __builtin_amdgcn_global_load_lds(
        (const __attribute__((address_space(1))) unsigned int*)g,
        (__attribute__((address_space(3))) unsigned int*)l, 16, 0, 0);
}

// ======================= FAST PATH =======================

// k_prepc: fused prep+center (round-1's verified fusion, ebf store removed).
// One block per speaker, 512 thr. Row sums (in-block), q = ||e||^2 -> qg,
// normalized centroid -> cbf, ||S||^2 / ||S|| -> n2g/n1g. No ebf, no Sp.
__global__ void __launch_bounds__(512) k_prepc(const float* __restrict__ emb,
                                               unsigned short* __restrict__ cbf,
                                               float* __restrict__ qg,
                                               float* __restrict__ n2g,
                                               float* __restrict__ n1g) {
    const int j = blockIdx.x;
    const int t = threadIdx.x;
    const int cg = t & 255;          // 4-col group
    const int half = t >> 8;         // rows 0..31 / 32..63
    const int lane = t & 63, wave = t >> 6;     // wave 0..7
    const size_t rb = (size_t)j * MUTT + (size_t)half * 32;
    const float* src = emb + rb * DDIM + (size_t)cg * 4;
    __shared__ float qws[64][4];
    __shared__ float4 csum[256];
    __shared__ float red[4];
    __shared__ float sc_sh;
    float4 s = make_float4(0.f, 0.f, 0.f, 0.f);
    #pragma unroll 8
    for (int m = 0; m < 32; ++m) {
        float4 v = *(const float4*)(src + (size_t)m * DDIM);
        s.x += v.x; s.y += v.y; s.z += v.z; s.w += v.w;
        float qp = v.x * v.x + v.y * v.y + v.z * v.z + v.w * v.w;
        #pragma unroll
        for (int off = 32; off > 0; off >>= 1) qp += __shfl_down(qp, off, 64);
        if (lane == 0) qws[half * 32 + m][wave & 3] = qp;   // 4 waves per half
    }
    if (half) csum[cg] = s;          // upper half publishes its partial sum
    __syncthreads();
    if (t < 64) qg[(size_t)j * MUTT + t] = qws[t][0] + qws[t][1] + qws[t][2] + qws[t][3];
    if (!half) {
        float4 c = csum[cg];
        s.x += c.x; s.y += c.y; s.z += c.z; s.w += c.w;   // full speaker sum S
        float sq = s.x * s.x + s.y * s.y + s.z * s.z + s.w * s.w;
        #pragma unroll
        for (int off = 32; off > 0; off >>= 1) sq += __shfl_down(sq, off, 64);
        if (lane == 0) red[wave] = sq;                     // waves 0..3
    }
    __syncthreads();
    if (t == 0) {
        float tot = red[0] + red[1] + red[2] + red[3];     // ||S||^2
        n2g[j] = tot;
        n1g[j] = sqrtf(tot);
        float msq = tot * (1.0f / 4096.0f);                // ||S/64||^2
        sc_sh = rsqrtf(fmaxf(msq, 1e-12f)) * (1.0f / 64.0f);
    }
    __syncthreads();
    if (!half) {
        const float sc = sc_sh;                            // = 1/||S|| (above eps)
        *(uint2*)(cbf + (size_t)j * DDIM + (size_t)cg * 4) =
            make_uint2(pack2(s.x * sc, s.y * sc), pack2(s.z * sc, s.w * sc));
    }
}

// k_gemmf: block j = speaker j -> 64 rows x all 256 cols. A = emb fp32 staged
// once (reg-load -> pack2 -> ds_write, T14 issue-early/write-late); B = cbf
// bf16 k-slice via gload16. BK=64, 16 iters, 3 LDS buffers (120 KB), counted
// vmcnt (stage t+2 in flight during compute t), ONE barrier per iter.
// 4 waves x (64x64 via 2x2 mfma_32x32x16) -> 16 ds_read_b128/wave/iter.
// XOR swizzle chunk^(row&7): 2-way-banked b128 reads = free.
__global__ void __launch_bounds__(256)
k_gemmf(const float* __restrict__ emb, const unsigned short* __restrict__ cbf,
        const float* __restrict__ qg, const float* __restrict__ n2g,
        const float* __restrict__ n1g,
        const float* __restrict__ wp, const float* __restrict__ bp,
        float* __restrict__ out) {
    // per buffer: A 64x64 bf16 = 8 KB (4096 shorts) + B 256x64 bf16 = 32 KB
    __shared__ unsigned short lds[3 * 20480];   // 120 KB

    const int tid = threadIdx.x, lane = tid & 63, wave = tid >> 6;
    const int j = blockIdx.x;
    const int row0 = j * 64;

    // ---- A staging geometry (fp32 -> regs -> bf16 -> ds_write) ----
    // slot c in [0,512): row = c>>3 (64 rows via c and c+256), sw = c&7.
    // LDS slot (row,sw) holds global chunk g = sw ^ (row&7)  (8 bf16 = 16 B).
    const int arow = tid >> 3;                  // 0..31 (and +32 for c+256)
    const int ga = (tid & 7) ^ (arow & 7);      // same for row and row+32
    const float* ap0 = emb + (size_t)(row0 + arow) * DDIM + ga * 8;
    const float* ap1 = ap0 + (size_t)32 * DDIM;

    // ---- B staging geometry (gload16) ----
    // batch i: rows i*32 + (tid>>3), sw = tid&7 ; g = sw ^ (row&7) (i-indep).
    const int bbase = arow * DDIM + ga * 8;     // shorts; + i*32*DDIM + t*64

    // ---- fragment geometry ----
    const int l31 = lane & 31, l5 = lane >> 5;
    // A rows: rr*32 + l31 ; B rows (=cols of C): wave*64 + cc*32 + l31.

    frag_c16 acc[2][2];
    #pragma unroll
    for (int rr = 0; rr < 2; ++rr)
        #pragma unroll
        for (int cc = 0; cc < 2; ++cc)
            #pragma unroll
            for (int q = 0; q < 16; ++q) acc[rr][cc][q] = 0.f;

    float4 rA[2][4];   // 2-deep A register pipeline

    // issue stage t: 4 fp32 A-loads (12.. the 4 newest) + 8 B gload16 = 12 vmem ops
    auto issueS = [&](int t, float4 ra[4]) {
        const int ko = t * 64;                          // element k-offset
        ra[0] = *(const float4*)(ap0 + ko);
        ra[1] = *(const float4*)(ap0 + ko + 4);
        ra[2] = *(const float4*)(ap1 + ko);
        ra[3] = *(const float4*)(ap1 + ko + 4);
        unsigned short* LB = &lds[(t % 3) * 20480 + 4096];
        #pragma unroll
        for (int i = 0; i < 8; ++i)
            gload16(cbf + (size_t)bbase + (size_t)i * 32 * DDIM + ko,
                    LB + ((size_t)i * 256 + tid) * 8);
    };
    auto writeA = [&](int t, float4 ra[4]) {
        unsigned short* LA = &lds[(t % 3) * 20480];
        uint4 p0 = make_uint4(pack2(ra[0].x, ra[0].y), pack2(ra[0].z, ra[0].w),
                              pack2(ra[1].x, ra[1].y), pack2(ra[1].z, ra[1].w));
        uint4 p1 = make_uint4(pack2(ra[2].x, ra[2].y), pack2(ra[2].z, ra[2].w),
                              pack2(ra[3].x, ra[3].y), pack2(ra[3].z, ra[3].w));
        *(uint4*)&LA[(size_t)tid * 8] = p0;
        *(uint4*)&LA[((size_t)tid + 256) * 8] = p1;
    };

    // prologue: tiles 0,1 in flight; write A0; one barrier
    issueS(0, rA[0]);
    issueS(1, rA[1]);
    asm volatile("s_waitcnt vmcnt(12)" ::: "memory");   // tile 0 landed
    writeA(0, rA[0]);
    asm volatile("s_waitcnt lgkmcnt(0)" ::: "memory");
    __builtin_amdgcn_s_barrier();
    __builtin_amdgcn_sched_barrier(0);

    const int NIT = DDIM / 64;   // 16
    #pragma unroll
    for (int t = 0; t < NIT; ++t) {
        if (t + 2 < NIT) issueS(t + 2, rA[t & 1]);   // (t+2)&1 == t&1

        // compute tile t from buffer t%3
        const unsigned short* L  = &lds[(t % 3) * 20480];
        const unsigned short* LB = L + 4096;
        #pragma unroll
        for (int ks = 0; ks < 4; ++ks) {
            const int kc = 2 * ks + l5;              // chunk-in-row 0..7
            frag_ab af[2], bfr[2];
            #pragma unroll
            for (int rr = 0; rr < 2; ++rr) {
                int r = rr * 32 + l31;
                af[rr] = *(const frag_ab*)&L[r * 64 + ((kc ^ (r & 7)) << 3)];
            }
            #pragma unroll
            for (int cc = 0; cc < 2; ++cc) {
                int r = wave * 64 + cc * 32 + l31;
                bfr[cc] = *(const frag_ab*)&LB[r * 64 + ((kc ^ (r & 7)) << 3)];
            }
            #pragma unroll
            for (int rr = 0; rr < 2; ++rr)
                #pragma unroll
                for (int cc = 0; cc < 2; ++cc)
                    acc[rr][cc] = __builtin_amdgcn_mfma_f32_32x32x16_bf16(
                        af[rr], bfr[cc], acc[rr][cc], 0, 0, 0);
        }

        if (t < NIT - 1) {
            // wait for tile t+1's 12 ops (keep t+2's 12 in flight if any)
            if (t + 2 < NIT) asm volatile("s_waitcnt vmcnt(12)" ::: "memory");
            else             asm volatile("s_waitcnt vmcnt(0)"  ::: "memory");
            writeA(t + 1, rA[(t + 1) & 1]);
            asm volatile("s_waitcnt lgkmcnt(0)" ::: "memory");
            __builtin_amdgcn_s_barrier();
            __builtin_amdgcn_sched_barrier(0);
        }
    }

    // epilogue (row mapping verified in round-2's passing kernel)
    const float wv = wp[0], bv = bp[0];
    const float ns2 = n2g[j], ns = n1g[j];
    #pragma unroll
    for (int rr = 0; rr < 2; ++rr) {
        #pragma unroll
        for (int cc = 0; cc < 2; ++cc) {
            frag_c16 v = acc[rr][cc];
            const int col = wave * 64 + cc * 32 + l31;
            #pragma unroll
            for (int r = 0; r < 16; ++r) {
                int grow = row0 + rr * 32 + (r & 3) + 8 * (r >> 2) + 4 * l5;
                float val = v[r];
                if (col == j) {
                    float q = qg[grow];
                    float rd = val * ns;
                    float den2 = ns2 - 2.f * rd + q;
                    val = (rd - q) * rsqrtf(fmaxf(den2, 1e-12f));
                }
                out[(size_t)grow * NSPK + col] = wv * val + bv;
            }
        }
    }
}

// ======================= FALLBACK (small ws) =======================

__global__ void k_sums(const float* __restrict__ emb, float* __restrict__ Sp) {
    const int j = blockIdx.x;
    const int h = blockIdx.y;
    const int c = threadIdx.x;
    const float* base = emb + ((size_t)j * MUTT + (size_t)h * 32) * DDIM + (size_t)c * 4;
    float4 acc = make_float4(0.f, 0.f, 0.f, 0.f);
    #pragma unroll 8
    for (int m = 0; m < 32; ++m) {
        float4 v = *(const float4*)(base + (size_t)m * DDIM);
        acc.x += v.x; acc.y += v.y; acc.z += v.z; acc.w += v.w;
    }
    *(float4*)(Sp + ((size_t)h * NSPK + j) * DDIM + (size_t)c * 4) = acc;
}

template <int P>
__global__ void k_center(const float* __restrict__ Sp, unsigned short* __restrict__ cbf,
                         float* __restrict__ normS2g, float* __restrict__ normSg) {
    const int j = blockIdx.x;
    const int t = threadIdx.x;
    float4 v = make_float4(0.f, 0.f, 0.f, 0.f);
    #pragma unroll
    for (int p = 0; p < P; ++p) {
        float4 a = *(const float4*)(Sp + ((size_t)p * NSPK + j) * DDIM + (size_t)t * 4);
        v.x += a.x; v.y += a.y; v.z += a.z; v.w += a.w;
    }
    float sq = v.x * v.x + v.y * v.y + v.z * v.z + v.w * v.w;
    #pragma unroll
    for (int off = 32; off > 0; off >>= 1) sq += __shfl_down(sq, off, 64);
    __shared__ float ws[4];
    __shared__ float sc_sh;
    const int lane = t & 63, wave = t >> 6;
    if (lane == 0) ws[wave] = sq;
    __syncthreads();
    if (t == 0) {
        float tot = ws[0] + ws[1] + ws[2] + ws[3];
        normS2g[j] = tot;
        normSg[j]  = sqrtf(tot);
        float msq = tot * (1.0f / 4096.0f);
        sc_sh = rsqrtf(fmaxf(msq, 1e-12f)) * (1.0f / 64.0f);
    }
    __syncthreads();
    const float sc = sc_sh;
    *(uint2*)(cbf + (size_t)j * DDIM + (size_t)t * 4) =
        make_uint2(pack2(v.x * sc, v.y * sc), pack2(v.z * sc, v.w * sc));
}

__global__ void __launch_bounds__(256)
k_gemm_old(const float* __restrict__ emb, const unsigned short* __restrict__ cbf,
           const float* __restrict__ normS2g, const float* __restrict__ normSg,
           const float* __restrict__ wp, const float* __restrict__ bp,
           float* __restrict__ out) {
    __shared__ unsigned short Asm[32][32];
    __shared__ unsigned short Bsm[256][32];
    __shared__ float qpart[32][8];
    __shared__ float qfin[32];
    const int tid = threadIdx.x, lane = tid & 63, wave = tid >> 6;
    const int row0 = blockIdx.x * 32;
    const int jspk = row0 >> 6;
    frag_cd acc[2][4];
    #pragma unroll
    for (int rr = 0; rr < 2; ++rr)
        #pragma unroll
        for (int cc = 0; cc < 4; ++cc) acc[rr][cc] = (frag_cd){0.f, 0.f, 0.f, 0.f};
    const int ar = tid >> 3, ak = (tid & 7) << 2;
    const float* aptr = emb + (size_t)(row0 + ar) * DDIM + ak;
    float qacc = 0.f;
    const int bi = tid >> 2, bk = (tid & 3) << 3;
    const int am = lane & 15, kq = (lane >> 4) << 3;
    for (int k0 = 0; k0 < DDIM; k0 += 32) {
        __syncthreads();
        float4 av = *(const float4*)(aptr + k0);
        qacc += av.x * av.x + av.y * av.y + av.z * av.z + av.w * av.w;
        *(uint2*)&Asm[ar][ak] = make_uint2(pack2(av.x, av.y), pack2(av.z, av.w));
        #pragma unroll
        for (int p = 0; p < 4; ++p) {
            int brow = p * 64 + bi;
            *(uint4*)&Bsm[brow][bk] = *(const uint4*)(cbf + (size_t)brow * DDIM + k0 + bk);
        }
        __syncthreads();
        frag_ab afr[2], bfr[4];
        #pragma unroll
        for (int rr = 0; rr < 2; ++rr) afr[rr] = *(const frag_ab*)&Asm[rr * 16 + am][kq];
        #pragma unroll
        for (int cc = 0; cc < 4; ++cc) bfr[cc] = *(const frag_ab*)&Bsm[wave * 64 + cc * 16 + am][kq];
        #pragma unroll
        for (int rr = 0; rr < 2; ++rr)
            #pragma unroll
            for (int cc = 0; cc < 4; ++cc)
                acc[rr][cc] = __builtin_amdgcn_mfma_f32_16x16x32_bf16(afr[rr], bfr[cc], acc[rr][cc], 0, 0, 0);
    }
    qpart[ar][tid & 7] = qacc;
    __syncthreads();
    if (tid < 32) {
        float s = 0.f;
        #pragma unroll
        for (int u = 0; u < 8; ++u) s += qpart[tid][u];
        qfin[tid] = s;
    }
    __syncthreads();
    const float wv = wp[0], bv = bp[0];
    const float ns2 = normS2g[jspk], ns = normSg[jspk];
    #pragma unroll
    for (int rr = 0; rr < 2; ++rr) {
        int rbase = rr * 16 + ((lane >> 4) << 2);
        #pragma unroll
        for (int cc = 0; cc < 4; ++cc) {
            int col = wave * 64 + cc * 16 + (lane & 15);
            frag_cd v = acc[rr][cc];
            #pragma unroll
            for (int r2 = 0; r2 < 4; ++r2) {
                int lrow = rbase + r2;
                float val = v[r2];
                if (col == jspk) {
                    float q = qfin[lrow];
                    float rd = val * ns;
                    float den2 = ns2 - 2.f * rd + q;
                    val = (rd - q) * rsqrtf(fmaxf(den2, 1e-12f));
                }
                out[(size_t)(row0 + lrow) * NSPK + col] = wv * val + bv;
            }
        }
    }
}

extern "C" void kernel_launch(void* const* d_in, const int* in_sizes, int n_in,
                              void* d_out, int out_size, void* d_ws, size_t ws_size,
                              hipStream_t stream) {
    const float* emb = (const float*)d_in[0];
    const float* w   = (const float*)d_in[1];
    const float* b   = (const float*)d_in[2];
    float* out = (float*)d_out;

    const size_t sz_cbf = (size_t)NSPK * DDIM * 2;     // 512 KB
    const size_t sz_qg  = (size_t)NROW * 4;            // 64 KB
    const size_t need = sz_cbf + sz_qg + 2 * NSPK * 4;

    if (ws_size >= need) {
        char* p = (char*)d_ws;
        unsigned short* cbf = (unsigned short*)p; p += sz_cbf;
        float* qg = (float*)p;                    p += sz_qg;
        float* n2 = (float*)p;
        float* n1 = n2 + NSPK;
        k_prepc<<<NSPK, 512, 0, stream>>>(emb, cbf, qg, n2, n1);
        k_gemmf<<<NSPK, 256, 0, stream>>>(emb, cbf, qg, n2, n1, w, b, out);
    } else {
        float* Sp = (float*)d_ws;
        unsigned short* cbf = (unsigned short*)(Sp + 2 * NSPK * DDIM);
        float* n2 = (float*)(cbf + NSPK * DDIM);
        float* n1 = n2 + NSPK;
        k_sums<<<dim3(NSPK, 2), 256, 0, stream>>>(emb, Sp);
        k_center<2><<<NSPK, 256, 0, stream>>>(Sp, cbf, n2, n1);
        k_gemm_old<<<NROW / 32, 256, 0, stream>>>(emb, cbf, n2, n1, w, b, out);
    }
}

// Round 4
// 127.484 us; speedup vs baseline: 1.1271x; 1.1271x over previous
//
#include <hip/hip_runtime.h>

#define NSPK 256
#define MUTT 64
#define DDIM 1024
#define NROW (NSPK * MUTT)   // 16384

using frag_ab = __attribute__((ext_vector_type(8))) short;   // 8 bf16 (4 VGPRs)
using frag_cd = __attribute__((ext_vector_type(4))) float;   // 4 fp32 acc

static __device__ __forceinline__ unsigned short f32_to_bf16(float f) {
    unsigned int u = __float_as_uint(f);
    return (unsigned short)((u + 0x7FFFu + ((u >> 16) & 1u)) >> 16);   // RNE
}
static __device__ __forceinline__ unsigned int pack2(float a, float b) {
    return (unsigned)f32_to_bf16(a) | ((unsigned)f32_to_bf16(b) << 16);
}
static __device__ __forceinline__ void gload16(const void* g, void* l) {
    __builtin_amdgcn_global_load_lds(
        (const __attribute__((address_space(1))) unsigned int*)g,
        (__attribute__((address_space(3))) unsigned int*)l, 16, 0, 0);
}

// ======================= FAST PATH =======================

// k_prep (round-0 proven, 126.1us config): grid (NSPK, 4), 256 thr,
// 16 rows/block, 4 blocks/CU.
__global__ void __launch_bounds__(256) k_prep(const float* __restrict__ emb,
                                              float* __restrict__ Sp,
                                              unsigned short* __restrict__ ebf,
                                              float* __restrict__ qg) {
    const int j = blockIdx.x;
    const int h = blockIdx.y;
    const int t = threadIdx.x;
    const int lane = t & 63, wave = t >> 6;
    const size_t rowbase = (size_t)j * MUTT + (size_t)h * 16;
    const float* src = emb + rowbase * DDIM + (size_t)t * 4;
    unsigned short* edst = ebf + rowbase * DDIM + (size_t)t * 4;
    __shared__ float qws[16][4];
    float4 s = make_float4(0.f, 0.f, 0.f, 0.f);
    #pragma unroll
    for (int m = 0; m < 16; ++m) {
        float4 v = *(const float4*)(src + (size_t)m * DDIM);
        s.x += v.x; s.y += v.y; s.z += v.z; s.w += v.w;
        float qp = v.x * v.x + v.y * v.y + v.z * v.z + v.w * v.w;
        #pragma unroll
        for (int off = 32; off > 0; off >>= 1) qp += __shfl_down(qp, off, 64);
        if (lane == 0) qws[m][wave] = qp;
        *(uint2*)(edst + (size_t)m * DDIM) = make_uint2(pack2(v.x, v.y), pack2(v.z, v.w));
    }
    __syncthreads();
    if (t < 16) qg[rowbase + t] = qws[t][0] + qws[t][1] + qws[t][2] + qws[t][3];
    *(float4*)(Sp + ((size_t)h * NSPK + j) * DDIM + (size_t)t * 4) = s;
}

template <int P>
__global__ void k_center(const float* __restrict__ Sp, unsigned short* __restrict__ cbf,
                         float* __restrict__ normS2g, float* __restrict__ normSg) {
    const int j = blockIdx.x;
    const int t = threadIdx.x;
    float4 v = make_float4(0.f, 0.f, 0.f, 0.f);
    #pragma unroll
    for (int p = 0; p < P; ++p) {
        float4 a = *(const float4*)(Sp + ((size_t)p * NSPK + j) * DDIM + (size_t)t * 4);
        v.x += a.x; v.y += a.y; v.z += a.z; v.w += a.w;
    }
    float sq = v.x * v.x + v.y * v.y + v.z * v.z + v.w * v.w;
    #pragma unroll
    for (int off = 32; off > 0; off >>= 1) sq += __shfl_down(sq, off, 64);
    __shared__ float ws[4];
    __shared__ float sc_sh;
    const int lane = t & 63, wave = t >> 6;
    if (lane == 0) ws[wave] = sq;
    __syncthreads();
    if (t == 0) {
        float tot = ws[0] + ws[1] + ws[2] + ws[3];
        normS2g[j] = tot;
        normSg[j]  = sqrtf(tot);
        float msq = tot * (1.0f / 4096.0f);
        sc_sh = rsqrtf(fmaxf(msq, 1e-12f)) * (1.0f / 64.0f);
    }
    __syncthreads();
    const float sc = sc_sh;
    *(uint2*)(cbf + (size_t)j * DDIM + (size_t)t * 4) =
        make_uint2(pack2(v.x * sc, v.y * sc), pack2(v.z * sc, v.w * sc));
}

// k_gemm4: round-0 structure (64x64 tile, BK=64, grid (256,4), 32 KB LDS,
// 4-5 blocks/CU) with ONE change: the per-iter __syncthreads() (which drains
// the just-issued prefetch DMA, vmcnt(0)) is replaced by the round-2-verified
// counted-vmcnt schedule: s_waitcnt vmcnt(4) waits only for tile t's 4 loads;
// tile t+1's 4 stay in flight across both raw barriers. vmcnt hits 0 only at
// the final iteration. XOR swizzle (chunk ^= row&7) -> conflict-free b128.
#define BK 64
__global__ void __launch_bounds__(256, 5)
k_gemm4(const unsigned short* __restrict__ ebf, const unsigned short* __restrict__ cbf,
        const float* __restrict__ qg, const float* __restrict__ n2g,
        const float* __restrict__ n1g,
        const float* __restrict__ wp, const float* __restrict__ bp,
        float* __restrict__ out) {
    __shared__ unsigned short lds[2 * 8192];   // 2 buffers x (A 4096 + B 4096 shorts)

    const int tid = threadIdx.x, lane = tid & 63, wave = tid >> 6;
    const int rt = blockIdx.x;            // speaker / 64-row tile
    const int ct = blockIdx.y;            // 64-col tile
    const int row0 = rt * 64;
    const int c0 = ct * 64;
    const int jspk = rt;

    // staging offsets: chunk = 16 B; row has 8 chunks (BK=64 bf16 = 128 B).
    // LDS chunk (row, sw) holds G[row][sw ^ (row&7)].
    int goff[2];
    #pragma unroll
    for (int i = 0; i < 2; ++i) {
        int c = i * 256 + tid, row = c >> 3, sw = c & 7;
        goff[i] = row * (DDIM * 2) + ((sw ^ (row & 7)) << 4);
    }
    const int stbase = wave * 512;        // shorts; wave-uniform LDS base
    const char* agbase = (const char*)(ebf + (size_t)row0 * DDIM);
    const char* bgbase = (const char*)(cbf + (size_t)c0 * DDIM);

    const int quad = lane >> 4;
    const int m16 = lane & 15;
    const int wrow = wave >> 1, wcol = wave & 1;   // 2x2 wave grid, 32x32 each
    int arow[2], brow[2];
    #pragma unroll
    for (int rr = 0; rr < 2; ++rr) arow[rr] = wrow * 32 + rr * 16 + m16;
    #pragma unroll
    for (int cc = 0; cc < 2; ++cc) brow[cc] = wcol * 32 + cc * 16 + m16;

    frag_cd acc[2][2];
    #pragma unroll
    for (int rr = 0; rr < 2; ++rr)
        #pragma unroll
        for (int cc = 0; cc < 2; ++cc) acc[rr][cc] = (frag_cd){0.f, 0.f, 0.f, 0.f};

    // stage K-tile kt into LDS buffer buf (4 gload16 per thread)
    auto stage = [&](int buf, int kt) {
        const char* ag = agbase + (size_t)kt * BK * 2;
        const char* bg = bgbase + (size_t)kt * BK * 2;
        unsigned short* Ld = &lds[buf * 8192];
        #pragma unroll
        for (int i = 0; i < 2; ++i) {
            gload16(ag + goff[i], Ld + i * 2048 + stbase);
            gload16(bg + goff[i], Ld + 4096 + i * 2048 + stbase);
        }
    };

    // prologue: tiles 0 and 1 in flight (8 outstanding loads/wave)
    stage(0, 0);
    stage(1, 1);

    const int NIT = DDIM / BK;   // 16
    for (int it = 0; it < NIT; ++it) {
        // tile `it` landed (all but the newest 4 loads); keep tile it+1 in flight
        if (it < NIT - 1) asm volatile("s_waitcnt vmcnt(4)" ::: "memory");
        else              asm volatile("s_waitcnt vmcnt(0)" ::: "memory");
        __builtin_amdgcn_s_barrier();
        __builtin_amdgcn_sched_barrier(0);

        const unsigned short* L = &lds[(it & 1) * 8192];
        #pragma unroll
        for (int s = 0; s < 2; ++s) {
            frag_ab af[2], bf[2];
            const int kc = (s << 2) + quad;            // chunk-in-row 0..7
            #pragma unroll
            for (int rr = 0; rr < 2; ++rr) {
                int addr = arow[rr] * 128 + ((kc ^ (arow[rr] & 7)) << 4);
                af[rr] = *(const frag_ab*)&L[addr >> 1];
            }
            #pragma unroll
            for (int cc = 0; cc < 2; ++cc) {
                int addr = 8192 + brow[cc] * 128 + ((kc ^ (brow[cc] & 7)) << 4);
                bf[cc] = *(const frag_ab*)&L[addr >> 1];
            }
            #pragma unroll
            for (int rr = 0; rr < 2; ++rr)
                #pragma unroll
                for (int cc = 0; cc < 2; ++cc)
                    acc[rr][cc] = __builtin_amdgcn_mfma_f32_16x16x32_bf16(
                        af[rr], bf[cc], acc[rr][cc], 0, 0, 0);
        }

        __builtin_amdgcn_s_barrier();          // all waves done reading buf[it&1]
        __builtin_amdgcn_sched_barrier(0);
        if (it + 2 < NIT) stage(it & 1, it + 2);   // overwrite now-free buffer
    }

    const float wv = wp[0], bv = bp[0];
    const float ns2 = n2g[jspk], ns = n1g[jspk];
    #pragma unroll
    for (int rr = 0; rr < 2; ++rr) {
        int rbase = wrow * 32 + rr * 16 + (quad << 2);
        #pragma unroll
        for (int cc = 0; cc < 2; ++cc) {
            int col = c0 + wcol * 32 + cc * 16 + m16;
            frag_cd v = acc[rr][cc];
            #pragma unroll
            for (int r2 = 0; r2 < 4; ++r2) {
                int grow = row0 + rbase + r2;
                float val = v[r2];
                if (col == jspk) {
                    float q = qg[grow];
                    float rd = val * ns;
                    float den2 = ns2 - 2.f * rd + q;
                    val = (rd - q) * rsqrtf(fmaxf(den2, 1e-12f));
                }
                out[(size_t)grow * NSPK + col] = wv * val + bv;
            }
        }
    }
}

// ======================= FALLBACK (small ws) =======================

__global__ void k_sums(const float* __restrict__ emb, float* __restrict__ Sp) {
    const int j = blockIdx.x;
    const int h = blockIdx.y;
    const int c = threadIdx.x;
    const float* base = emb + ((size_t)j * MUTT + (size_t)h * 32) * DDIM + (size_t)c * 4;
    float4 acc = make_float4(0.f, 0.f, 0.f, 0.f);
    #pragma unroll 8
    for (int m = 0; m < 32; ++m) {
        float4 v = *(const float4*)(base + (size_t)m * DDIM);
        acc.x += v.x; acc.y += v.y; acc.z += v.z; acc.w += v.w;
    }
    *(float4*)(Sp + ((size_t)h * NSPK + j) * DDIM + (size_t)c * 4) = acc;
}

__global__ void __launch_bounds__(256)
k_gemm_old(const float* __restrict__ emb, const unsigned short* __restrict__ cbf,
           const float* __restrict__ normS2g, const float* __restrict__ normSg,
           const float* __restrict__ wp, const float* __restrict__ bp,
           float* __restrict__ out) {
    __shared__ unsigned short Asm[32][32];
    __shared__ unsigned short Bsm[256][32];
    __shared__ float qpart[32][8];
    __shared__ float qfin[32];
    const int tid = threadIdx.x, lane = tid & 63, wave = tid >> 6;
    const int row0 = blockIdx.x * 32;
    const int jspk = row0 >> 6;
    frag_cd acc[2][4];
    #pragma unroll
    for (int rr = 0; rr < 2; ++rr)
        #pragma unroll
        for (int cc = 0; cc < 4; ++cc) acc[rr][cc] = (frag_cd){0.f, 0.f, 0.f, 0.f};
    const int ar = tid >> 3, ak = (tid & 7) << 2;
    const float* aptr = emb + (size_t)(row0 + ar) * DDIM + ak;
    float qacc = 0.f;
    const int bi = tid >> 2, bk = (tid & 3) << 3;
    const int am = lane & 15, kq = (lane >> 4) << 3;
    for (int k0 = 0; k0 < DDIM; k0 += 32) {
        __syncthreads();
        float4 av = *(const float4*)(aptr + k0);
        qacc += av.x * av.x + av.y * av.y + av.z * av.z + av.w * av.w;
        *(uint2*)&Asm[ar][ak] = make_uint2(pack2(av.x, av.y), pack2(av.z, av.w));
        #pragma unroll
        for (int p = 0; p < 4; ++p) {
            int brow = p * 64 + bi;
            *(uint4*)&Bsm[brow][bk] = *(const uint4*)(cbf + (size_t)brow * DDIM + k0 + bk);
        }
        __syncthreads();
        frag_ab afr[2], bfr[4];
        #pragma unroll
        for (int rr = 0; rr < 2; ++rr) afr[rr] = *(const frag_ab*)&Asm[rr * 16 + am][kq];
        #pragma unroll
        for (int cc = 0; cc < 4; ++cc) bfr[cc] = *(const frag_ab*)&Bsm[wave * 64 + cc * 16 + am][kq];
        #pragma unroll
        for (int rr = 0; rr < 2; ++rr)
            #pragma unroll
            for (int cc = 0; cc < 4; ++cc)
                acc[rr][cc] = __builtin_amdgcn_mfma_f32_16x16x32_bf16(afr[rr], bfr[cc], acc[rr][cc], 0, 0, 0);
    }
    qpart[ar][tid & 7] = qacc;
    __syncthreads();
    if (tid < 32) {
        float s = 0.f;
        #pragma unroll
        for (int u = 0; u < 8; ++u) s += qpart[tid][u];
        qfin[tid] = s;
    }
    __syncthreads();
    const float wv = wp[0], bv = bp[0];
    const float ns2 = normS2g[jspk], ns = normSg[jspk];
    #pragma unroll
    for (int rr = 0; rr < 2; ++rr) {
        int rbase = rr * 16 + ((lane >> 4) << 2);
        #pragma unroll
        for (int cc = 0; cc < 4; ++cc) {
            int col = wave * 64 + cc * 16 + (lane & 15);
            frag_cd v = acc[rr][cc];
            #pragma unroll
            for (int r2 = 0; r2 < 4; ++r2) {
                int lrow = rbase + r2;
                float val = v[r2];
                if (col == jspk) {
                    float q = qfin[lrow];
                    float rd = val * ns;
                    float den2 = ns2 - 2.f * rd + q;
                    val = (rd - q) * rsqrtf(fmaxf(den2, 1e-12f));
                }
                out[(size_t)(row0 + lrow) * NSPK + col] = wv * val + bv;
            }
        }
    }
}

extern "C" void kernel_launch(void* const* d_in, const int* in_sizes, int n_in,
                              void* d_out, int out_size, void* d_ws, size_t ws_size,
                              hipStream_t stream) {
    const float* emb = (const float*)d_in[0];
    const float* w   = (const float*)d_in[1];
    const float* b   = (const float*)d_in[2];
    float* out = (float*)d_out;

    const size_t sz_Sp  = (size_t)4 * NSPK * DDIM * 4;   // 4 MB
    const size_t sz_ebf = (size_t)NROW * DDIM * 2;       // 32 MB
    const size_t sz_cbf = (size_t)NSPK * DDIM * 2;       // 512 KB
    const size_t sz_qg  = (size_t)NROW * 4;              // 64 KB
    const size_t need = sz_Sp + sz_ebf + sz_cbf + sz_qg + 2 * NSPK * 4;

    if (ws_size >= need) {
        char* p = (char*)d_ws;
        float* Sp = (float*)p;                    p += sz_Sp;
        unsigned short* ebf = (unsigned short*)p; p += sz_ebf;
        unsigned short* cbf = (unsigned short*)p; p += sz_cbf;
        float* qg = (float*)p;                    p += sz_qg;
        float* n2 = (float*)p;
        float* n1 = n2 + NSPK;
        k_prep<<<dim3(NSPK, 4), 256, 0, stream>>>(emb, Sp, ebf, qg);
        k_center<4><<<NSPK, 256, 0, stream>>>(Sp, cbf, n2, n1);
        k_gemm4<<<dim3(NSPK, 4), 256, 0, stream>>>(ebf, cbf, qg, n2, n1, w, b, out);
    } else {
        float* Sp = (float*)d_ws;
        unsigned short* cbf = (unsigned short*)(Sp + 2 * NSPK * DDIM);
        float* n2 = (float*)(cbf + NSPK * DDIM);
        float* n1 = n2 + NSPK;
        k_sums<<<dim3(NSPK, 2), 256, 0, stream>>>(emb, Sp);
        k_center<2><<<NSPK, 256, 0, stream>>>(Sp, cbf, n2, n1);
        k_gemm_old<<<NROW / 32, 256, 0, stream>>>(emb, cbf, n2, n1, w, b, out);
    }
}